// Round 10
// baseline (313.651 us; speedup 1.0000x reference)
//
#include <hip/hip_runtime.h>

// NCC loss: 1 - mean( cross^2 / (pvar*tvar + 1e-8) ) over 9^3 zero-padded
// box windows, input (4,1,160,160,160) fp32.
//
// R15: R14 post-mortem — TY=32 amortization WORKED per-step (1.46us/step for
// 2x outputs vs R9's 1.25) but VGPR 76->84 (S[5][8]+rr[8] in the red wave
// raised the shared allocation; 84+~92 AGPR ring = 176 > 170 budget of
// launch_bounds(384,3)) -> HW fit only 2 waves/EU -> 1 block/CU -> net loss.
// R15 = R14 with the reduction wave doing TWO sequential passes of R9's
// exact S[5][4] body (pass 0: rows q*4..q*4+3; pass 1: 16+q*4..16+q*4+3).
// Red-path +~350cy is off-critical; register footprint back to R9's
// 76+92=168 <= 170 -> 2 blocks/CU restored at TY=32.
// Spill tripwire: WRITE_SIZE ~25-50KB. Occupancy tripwire: must be >20%.

#define DSZ    160
#define NBATCH 4
#define RAD    4
#define TX     16
#define TY     32
#define ZCHUNK 40
#define SLICE  (DSZ*DSZ)
#define VOL    (DSZ*DSZ*DSZ)
#define WINV   (1.0f/729.0f)
#define NVOX_INV (1.0f/16384000.0f)

#define NROW 40        // halo rows per tile (TY + 2*RAD)
#define NGRP 6         // x groups of 4 halo cols (24)
#define BLK  384       // 5 staging waves (tid<320) + 1 reduction wave

#define S2_RS 22                 // row stride: 16 outputs + pad (2-way banks)
#define S2_FS (NROW*S2_RS)       // 880 floats per field
#define S2_BUF (5*S2_FS)         // 4400 floats per parity buffer

__device__ __forceinline__ float dpp_shl1(float x) {  // lane i <- lane i+1 (16-lane row, OOB=0)
    return __int_as_float(__builtin_amdgcn_update_dpp(0, __float_as_int(x), 0x101, 0xf, 0xf, true));
}
__device__ __forceinline__ float dpp_shl2(float x) {  // lane i <- lane i+2
    return __int_as_float(__builtin_amdgcn_update_dpp(0, __float_as_int(x), 0x102, 0xf, 0xf, true));
}

__global__ __launch_bounds__(BLK, 3)
void ncc_main(const float* __restrict__ pred, const float* __restrict__ tgt,
              float* __restrict__ accum)
{
    const int tid = threadIdx.x;
    const int row = tid >> 3;      // 0..47 (staging uses 0..39)
    const int g   = tid & 7;       // 0..7; g<6 = active x-group
    const int ox  = blockIdx.x * TX;
    const int oy  = blockIdx.y * TY;
    const int batch = blockIdx.z >> 2;
    const int z0  = (blockIdx.z & 3) * ZCHUNK;

    __shared__ float s2[2*S2_BUF];   // 35.2 KB, double-buffered [f][y][x pad22]

    const bool stg = (tid < 320) && (g < NGRP);
    const bool red = (tid >= 320);               // dedicated reduction wave
    const int  gy  = oy - RAD + row;
    const int  gx0 = ox - RAD + g*4;
    const bool ldok = stg && (gy >= 0) && (gy < DSZ) && (gx0 >= 0) && (gx0 + 3 < DSZ);
    const int  base = batch*VOL + gy*DSZ + gx0;  // only used under ldok

    // register ring of raw slice values (own 4 columns), chunk-local slots
    float rp[9][4], rt[9][4];
    float zs[5][4];
    #pragma unroll
    for (int k = 0; k < 9; ++k)
        #pragma unroll
        for (int j = 0; j < 4; ++j) { rp[k][j] = 0.f; rt[k][j] = 0.f; }
    #pragma unroll
    for (int f = 0; f < 5; ++f)
        #pragma unroll
        for (int j = 0; j < 4; ++j) zs[f][j] = 0.f;

    // ---- warm-up: chunk-local slices 0..7 (z = z0-4 .. z0+3) -> slots 0..7
    if (stg) {
        #pragma unroll
        for (int i = 0; i < 8; ++i) {
            int z = z0 - RAD + i;
            if (z >= 0) {                       // uniform; z < DSZ always here
                float4 p4 = {0,0,0,0}, t4 = {0,0,0,0};
                if (ldok) {
                    p4 = *(const float4*)(pred + base + z*SLICE);
                    t4 = *(const float4*)(tgt  + base + z*SLICE);
                }
                const float pc[4] = {p4.x,p4.y,p4.z,p4.w};
                const float tc[4] = {t4.x,t4.y,t4.z,t4.w};
                #pragma unroll
                for (int j = 0; j < 4; ++j) {
                    zs[0][j] += pc[j];        zs[1][j] += tc[j];
                    zs[2][j] += pc[j]*pc[j];  zs[3][j] += tc[j]*tc[j];
                    zs[4][j] += pc[j]*tc[j];
                    rp[i][j] = pc[j];  rt[i][j] = tc[j];
                }
            }
        }
    }

    // ---- streaming prefetch of the next add-slice (depth 1) ----
    int za = z0 + RAD;                      // absolute z of next fetch
    int zmax = z0 + ZCHUNK + RAD;           // last useful slice + 1
    if (zmax > DSZ) zmax = DSZ;
    float4 pa4 = {0,0,0,0}, ta4 = {0,0,0,0};

#define PF_NEXT() do {                                                        \
    float4 _p = {0,0,0,0}, _t = {0,0,0,0};                                    \
    if (ldok && za < zmax) {                                                  \
        _p = *(const float4*)(pred + base + za*SLICE);                        \
        _t = *(const float4*)(tgt  + base + za*SLICE);                        \
    }                                                                         \
    pa4 = _p; ta4 = _t; ++za;                                                 \
} while (0)

    if (stg) PF_NEXT();  // slice for step 0

    int pb = 1;          // parity buffer toggle (first step -> 0)
    float acc = 0.f;

// R9's verified 4-output reduction pass (reads rows YQ..YQ+11)
#define REDPASS(YQ) do {                                                      \
    const int x = tid & 15;                                                   \
    const int yq = (YQ);                                                      \
    float S[5][4];                                                            \
    _Pragma("unroll")                                                         \
    for (int f = 0; f < 5; ++f) {                                             \
        const float* col = &s2w[f*S2_FS + x];                                 \
        float r0 = col[(yq+0)*S2_RS], r1 = col[(yq+1)*S2_RS];                 \
        float r2 = col[(yq+2)*S2_RS], r3 = col[(yq+3)*S2_RS];                 \
        float run = r0+r1+r2+r3 + col[(yq+4)*S2_RS] + col[(yq+5)*S2_RS]       \
                  + col[(yq+6)*S2_RS] + col[(yq+7)*S2_RS];                    \
        run += col[(yq+8)*S2_RS];        S[f][0] = run;                       \
        run += col[(yq+9)*S2_RS]  - r0;  S[f][1] = run;                       \
        run += col[(yq+10)*S2_RS] - r1;  S[f][2] = run;                       \
        run += col[(yq+11)*S2_RS] - r2;  S[f][3] = run;                       \
    }                                                                         \
    _Pragma("unroll")                                                         \
    for (int i = 0; i < 4; ++i) {                                             \
        float Sp = S[0][i], St = S[1][i];                                     \
        float cross = S[4][i] - Sp*St*WINV;                                   \
        float pv    = S[2][i] - Sp*Sp*WINV;                                   \
        float tv    = S[3][i] - St*St*WINV;                                   \
        acc += cross*cross / (pv*tv + 1e-8f);                                 \
    }                                                                         \
} while (0)

#define NCC_STEP(SLOT) do {                                                   \
    pb ^= 1;                                                                  \
    float* s2w = s2 + pb*S2_BUF;                                              \
    if (stg) {                                                                \
        const float pc[4] = {pa4.x,pa4.y,pa4.z,pa4.w};                        \
        const float tc[4] = {ta4.x,ta4.y,ta4.z,ta4.w};                        \
        PF_NEXT();  /* issue slice s+1; full step to complete */              \
        _Pragma("unroll")                                                     \
        for (int j = 0; j < 4; ++j) {                                         \
            float ps = rp[SLOT][j], qs = rt[SLOT][j];                         \
            float d0 = pc[j] - ps, d1 = tc[j] - qs;                           \
            zs[0][j] += d0;                                                   \
            zs[1][j] += d1;                                                   \
            zs[2][j] += d0*(pc[j] + ps);                                      \
            zs[3][j] += d1*(tc[j] + qs);                                      \
            zs[4][j] += pc[j]*tc[j] - ps*qs;                                  \
            rp[SLOT][j] = pc[j];  rt[SLOT][j] = tc[j];                        \
        }                                                                     \
        _Pragma("unroll")                                                     \
        for (int f = 0; f < 5; ++f) {                                         \
            float P0 = zs[f][0];                                              \
            float P1 = P0 + zs[f][1];                                         \
            float P2 = P1 + zs[f][2];                                         \
            float P3 = P2 + zs[f][3];                                         \
            float T  = dpp_shl1(P3);                                          \
            float Q0 = dpp_shl2(P0), Q1 = dpp_shl2(P1);                       \
            float Q2 = dpp_shl2(P2), Q3 = dpp_shl2(P3);                       \
            if (g < 4) {                                                      \
                float b = P3 + T;                                             \
                float* dst = &s2w[f*S2_FS + row*S2_RS + g*4];                 \
                dst[0] = b + Q0;                                              \
                dst[1] = b - P0 + Q1;                                         \
                dst[2] = b - P1 + Q2;                                         \
                dst[3] = b - P2 + Q3;                                         \
            }                                                                 \
        }                                                                     \
    }                                                                         \
    __syncthreads();                                                          \
    if (red) {                                                                \
        const int q = (tid >> 4) & 3;                                         \
        REDPASS(q*4);          /* output rows oy+q*4   .. oy+q*4+3  */        \
        REDPASS(16 + q*4);     /* output rows oy+16+q*4.. +3        */        \
    }                                                                         \
} while (0)

    // steps s=0..3: slots (s+8)%9 = 8,0,1,2
    NCC_STEP(8); NCC_STEP(0); NCC_STEP(1); NCC_STEP(2);
    // steps s=4..39: slot sequence (s+8)%9 is 9-periodic: 3,4,5,6,7,8,0,1,2
    for (int it = 0; it < 4; ++it) {
        NCC_STEP(3); NCC_STEP(4); NCC_STEP(5);
        NCC_STEP(6); NCC_STEP(7); NCC_STEP(8);
        NCC_STEP(0); NCC_STEP(1); NCC_STEP(2);
    }
#undef NCC_STEP
#undef REDPASS
#undef PF_NEXT

    // all cc partials live in the reduction wave (tid 320..383)
    if (red) {
        float v = acc;
        #pragma unroll
        for (int off = 32; off > 0; off >>= 1) v += __shfl_down(v, off, 64);
        if (tid == 320) atomicAdd(accum, v);
    }
}

__global__ void ncc_final(const float* __restrict__ accum, float* __restrict__ out)
{
    out[0] = 1.0f - accum[0] * NVOX_INV;
}

extern "C" void kernel_launch(void* const* d_in, const int* in_sizes, int n_in,
                              void* d_out, int out_size, void* d_ws, size_t ws_size,
                              hipStream_t stream)
{
    const float* pred = (const float*)d_in[0];
    const float* tgt  = (const float*)d_in[1];
    float* out = (float*)d_out;
    float* ws  = (float*)d_ws;

    hipMemsetAsync(ws, 0, sizeof(float), stream);
    dim3 grid(DSZ/TX, DSZ/TY, NBATCH*4);   // 10 x 5 x 16 = 800 blocks
    ncc_main<<<grid, BLK, 0, stream>>>(pred, tgt, ws);
    ncc_final<<<1, 1, 0, stream>>>(ws, out);
}

// Round 11
// 220.427 us; speedup vs baseline: 1.4229x; 1.4229x over previous
//
#include <hip/hip_runtime.h>

// NCC loss: 1 - mean( cross^2 / (pvar*tvar + 1e-8) ) over 9^3 zero-padded
// box windows, input (4,1,160,160,160) fp32.
//
// R16: R15 nailed the model — at >128 total regs/wave (arch VGPR + AGPR ring,
// unified file) the HW quantum is 2 waves/SIMD = 8 waves/CU; only R9's 4-wave
// block packs it (2 blocks/CU). To get more residency we must cross the
// 128-reg cliff, NOT grow the block. R16 = R9's exact structure (3 staging
// waves + 1 red wave, BLK 256, 40 steps, depth-1 prefetch, double-buffered
// s2, R9's red body verbatim) with 3 COLS/THREAD instead of 4:
//   - 24 halo cols = 8 groups x 3 -> ALL 8 lane-groups active (R9 idled 2/8).
//   - ring 72->54 floats, zs 20->15, prefetch 8->6 -> est ~115-125 total regs
//     <= 128 -> 4 waves/SIMD -> 4 blocks/CU (16 waves), desynced blocks hide
//     each other's barrier/latency stalls. launch_bounds(256,4) enforces.
//   - 3-col x-prefix via DPP shl1/shl2/shl3, all sources within the 8-lane
//     octet (max source m+3<=7 for consumed outputs): per field
//       v01=v0+v1; G=v01+v2; S=G+shl1(G)+shl2(G);
//       m<=4: out(3m)=S, out(3m+1)=S-v0+shl3(v0), out(3m+2)=S-v01+shl3(v01);
//       m==5: out(15)=S.
//   - per-thread chain ~same as R9 (~90 ops); bytes in flight/CU 12->18 KB.
// Tripwires: WRITE_SIZE ~25-50KB (spill); OccupancyPercent >=40% (if ~25%,
// regs exceeded 128 -> fallback launch_bounds(256,3) next round).

#define DSZ    160
#define NBATCH 4
#define RAD    4
#define TX     16
#define TY     16
#define ZCHUNK 40
#define SLICE  (DSZ*DSZ)
#define VOL    (DSZ*DSZ*DSZ)
#define WINV   (1.0f/729.0f)
#define NVOX_INV (1.0f/16384000.0f)

#define NROW 24        // halo rows per tile
#define BLK  256       // 3 staging waves (tid<192, all active) + 1 reduction wave

#define S2_RS 20                 // row stride: 16 outputs + pad
#define S2_FS (NROW*S2_RS)       // 480 floats per field
#define S2_BUF (5*S2_FS)         // 2400 floats per parity buffer

__device__ __forceinline__ float dpp_shl1(float x) {  // lane i <- lane i+1 (16-lane row, OOB=0)
    return __int_as_float(__builtin_amdgcn_update_dpp(0, __float_as_int(x), 0x101, 0xf, 0xf, true));
}
__device__ __forceinline__ float dpp_shl2(float x) {  // lane i <- lane i+2
    return __int_as_float(__builtin_amdgcn_update_dpp(0, __float_as_int(x), 0x102, 0xf, 0xf, true));
}
__device__ __forceinline__ float dpp_shl3(float x) {  // lane i <- lane i+3
    return __int_as_float(__builtin_amdgcn_update_dpp(0, __float_as_int(x), 0x103, 0xf, 0xf, true));
}

__global__ __launch_bounds__(BLK, 4)
void ncc_main(const float* __restrict__ pred, const float* __restrict__ tgt,
              float* __restrict__ accum)
{
    const int tid = threadIdx.x;
    const int row = tid >> 3;      // 0..23 halo row (staging threads)
    const int g   = tid & 7;       // 0..7 col-triple group; ALL active
    const int ox  = blockIdx.x * TX;
    const int oy  = blockIdx.y * TY;
    const int batch = blockIdx.z >> 2;
    const int z0  = (blockIdx.z & 3) * ZCHUNK;

    __shared__ float s2[2*S2_BUF];   // 19.2 KB, double-buffered [f][y][x pad20]

    const bool stg = (tid < 192);
    const bool red = (tid >= 192);               // dedicated reduction wave
    const int  gy  = oy - RAD + row;
    const int  gx0 = ox - RAD + g*3;             // 3 halo cols per thread
    const bool ldok = stg && (gy >= 0) && (gy < DSZ) && (gx0 >= 0) && (gx0 + 2 < DSZ);
    const int  base = batch*VOL + gy*DSZ + gx0;  // only used under ldok

    // register ring of raw slice values (own 3 columns), chunk-local slots
    float rp[9][3], rt[9][3];
    float zs[5][3];
    #pragma unroll
    for (int k = 0; k < 9; ++k)
        #pragma unroll
        for (int j = 0; j < 3; ++j) { rp[k][j] = 0.f; rt[k][j] = 0.f; }
    #pragma unroll
    for (int f = 0; f < 5; ++f)
        #pragma unroll
        for (int j = 0; j < 3; ++j) zs[f][j] = 0.f;

    // ---- warm-up: chunk-local slices 0..7 (z = z0-4 .. z0+3) -> slots 0..7
    if (stg) {
        #pragma unroll
        for (int i = 0; i < 8; ++i) {
            int z = z0 - RAD + i;
            if (z >= 0) {                       // uniform; z < DSZ always here
                float3 p3 = {0,0,0}, t3 = {0,0,0};
                if (ldok) {
                    p3 = *(const float3*)(pred + base + z*SLICE);
                    t3 = *(const float3*)(tgt  + base + z*SLICE);
                }
                const float pc[3] = {p3.x, p3.y, p3.z};
                const float tc[3] = {t3.x, t3.y, t3.z};
                #pragma unroll
                for (int j = 0; j < 3; ++j) {
                    zs[0][j] += pc[j];        zs[1][j] += tc[j];
                    zs[2][j] += pc[j]*pc[j];  zs[3][j] += tc[j]*tc[j];
                    zs[4][j] += pc[j]*tc[j];
                    rp[i][j] = pc[j];  rt[i][j] = tc[j];
                }
            }
        }
    }

    // ---- streaming prefetch of the next add-slice (depth 1) ----
    int za = z0 + RAD;                      // absolute z of next fetch
    int zmax = z0 + ZCHUNK + RAD;           // last useful slice + 1
    if (zmax > DSZ) zmax = DSZ;
    float3 pa3 = {0,0,0}, ta3 = {0,0,0};

#define PF_NEXT() do {                                                        \
    float3 _p = {0,0,0}, _t = {0,0,0};                                        \
    if (ldok && za < zmax) {                                                  \
        _p = *(const float3*)(pred + base + za*SLICE);                        \
        _t = *(const float3*)(tgt  + base + za*SLICE);                        \
    }                                                                         \
    pa3 = _p; ta3 = _t; ++za;                                                 \
} while (0)

    if (stg) PF_NEXT();  // slice for step 0

    int pb = 1;          // parity buffer toggle (first step -> 0)
    float acc = 0.f;

#define NCC_STEP(SLOT) do {                                                   \
    pb ^= 1;                                                                  \
    float* s2w = s2 + pb*S2_BUF;                                              \
    if (stg) {                                                                \
        const float pc[3] = {pa3.x, pa3.y, pa3.z};                            \
        const float tc[3] = {ta3.x, ta3.y, ta3.z};                            \
        PF_NEXT();  /* issue slice s+1; full step to complete */              \
        _Pragma("unroll")                                                     \
        for (int j = 0; j < 3; ++j) {                                         \
            float ps = rp[SLOT][j], qs = rt[SLOT][j];                         \
            float d0 = pc[j] - ps, d1 = tc[j] - qs;                           \
            zs[0][j] += d0;                                                   \
            zs[1][j] += d1;                                                   \
            zs[2][j] += d0*(pc[j] + ps);                                      \
            zs[3][j] += d1*(tc[j] + qs);                                      \
            zs[4][j] += pc[j]*tc[j] - ps*qs;                                  \
            rp[SLOT][j] = pc[j];  rt[SLOT][j] = tc[j];                        \
        }                                                                     \
        _Pragma("unroll")                                                     \
        for (int f = 0; f < 5; ++f) {                                         \
            float v0  = zs[f][0];                                             \
            float v01 = v0 + zs[f][1];                                        \
            float G   = v01 + zs[f][2];        /* 3-col group sum */          \
            float G1 = dpp_shl1(G);                                           \
            float G2 = dpp_shl2(G);                                           \
            float A0 = dpp_shl3(v0);           /* v0(m+3)  */                 \
            float A1 = dpp_shl3(v01);          /* v01(m+3) */                 \
            float S  = G + G1 + G2;            /* halo cols 3m..3m+8 */       \
            float* dst = &s2w[f*S2_FS + row*S2_RS + 3*g];                     \
            if (g < 5) {                                                      \
                dst[0] = S;                    /* out 3m   */                 \
                dst[1] = S - v0  + A0;         /* out 3m+1 */                 \
                dst[2] = S - v01 + A1;         /* out 3m+2 */                 \
            } else if (g == 5) {                                              \
                dst[0] = S;                    /* out 15   */                 \
            }                                                                 \
        }                                                                     \
    }                                                                         \
    __syncthreads();                                                          \
    if (red) {                                                                \
        const int x = tid & 15, yq = ((tid >> 4) & 3)*4;                      \
        float S[5][4];                                                        \
        _Pragma("unroll")                                                     \
        for (int f = 0; f < 5; ++f) {                                         \
            const float* col = &s2w[f*S2_FS + x];                             \
            float r0 = col[(yq+0)*S2_RS], r1 = col[(yq+1)*S2_RS];             \
            float r2 = col[(yq+2)*S2_RS], r3 = col[(yq+3)*S2_RS];             \
            float run = r0+r1+r2+r3 + col[(yq+4)*S2_RS] + col[(yq+5)*S2_RS]   \
                      + col[(yq+6)*S2_RS] + col[(yq+7)*S2_RS];                \
            run += col[(yq+8)*S2_RS];        S[f][0] = run;                   \
            run += col[(yq+9)*S2_RS]  - r0;  S[f][1] = run;                   \
            run += col[(yq+10)*S2_RS] - r1;  S[f][2] = run;                   \
            run += col[(yq+11)*S2_RS] - r2;  S[f][3] = run;                   \
        }                                                                     \
        _Pragma("unroll")                                                     \
        for (int i = 0; i < 4; ++i) {                                         \
            float Sp = S[0][i], St = S[1][i];                                 \
            float cross = S[4][i] - Sp*St*WINV;                               \
            float pv    = S[2][i] - Sp*Sp*WINV;                               \
            float tv    = S[3][i] - St*St*WINV;                               \
            acc += cross*cross / (pv*tv + 1e-8f);                             \
        }                                                                     \
    }                                                                         \
} while (0)

    // steps s=0..3: slots (s+8)%9 = 8,0,1,2
    NCC_STEP(8); NCC_STEP(0); NCC_STEP(1); NCC_STEP(2);
    // steps s=4..39: slot sequence (s+8)%9 is 9-periodic: 3,4,5,6,7,8,0,1,2
    for (int it = 0; it < 4; ++it) {
        NCC_STEP(3); NCC_STEP(4); NCC_STEP(5);
        NCC_STEP(6); NCC_STEP(7); NCC_STEP(8);
        NCC_STEP(0); NCC_STEP(1); NCC_STEP(2);
    }
#undef NCC_STEP
#undef PF_NEXT

    // all cc partials live in the reduction wave (tid 192..255)
    if (red) {
        float v = acc;
        #pragma unroll
        for (int off = 32; off > 0; off >>= 1) v += __shfl_down(v, off, 64);
        if (tid == 192) atomicAdd(accum, v);
    }
}

__global__ void ncc_final(const float* __restrict__ accum, float* __restrict__ out)
{
    out[0] = 1.0f - accum[0] * NVOX_INV;
}

extern "C" void kernel_launch(void* const* d_in, const int* in_sizes, int n_in,
                              void* d_out, int out_size, void* d_ws, size_t ws_size,
                              hipStream_t stream)
{
    const float* pred = (const float*)d_in[0];
    const float* tgt  = (const float*)d_in[1];
    float* out = (float*)d_out;
    float* ws  = (float*)d_ws;

    hipMemsetAsync(ws, 0, sizeof(float), stream);
    dim3 grid(DSZ/TX, DSZ/TY, NBATCH*4);   // 10 x 10 x 16 = 1600 blocks
    ncc_main<<<grid, BLK, 0, stream>>>(pred, tgt, ws);
    ncc_final<<<1, 1, 0, stream>>>(ws, out);
}